// Round 1
// baseline (605.264 us; speedup 1.0000x reference)
//
#include <hip/hip_runtime.h>

#define M_DIM 8192
#define N_DIM 4096
#define K_DIM 4096

typedef __attribute__((ext_vector_type(8))) short bf16x8;
typedef __attribute__((ext_vector_type(4))) float f32x4;

__device__ inline unsigned short f32_to_bf16_rne(float f) {
  unsigned int u = __float_as_uint(f);
  u += 0x7FFFu + ((u >> 16) & 1u);   // round-to-nearest-even
  return (unsigned short)(u >> 16);
}

// fp32 -> bf16 cast, 4 elements/thread, fully coalesced
__global__ void cvt_f32_bf16_kernel(const float* __restrict__ in,
                                    unsigned short* __restrict__ out) {
  const int i = (blockIdx.x * blockDim.x + threadIdx.x) * 4;
  float4 v = *(const float4*)(in + i);
  ushort4 o;
  o.x = f32_to_bf16_rne(v.x);
  o.y = f32_to_bf16_rne(v.y);
  o.z = f32_to_bf16_rne(v.z);
  o.w = f32_to_bf16_rne(v.w);
  *(ushort4*)(out + i) = o;
}

__device__ inline void gld_lds16(const void* g, void* l) {
  __builtin_amdgcn_global_load_lds(
      (__attribute__((address_space(1))) void*)(g),
      (__attribute__((address_space(3))) void*)(l),
      16, 0, 0);
}

// C[m][n] = sum_k A[m][k] * B[n][k]  (gemm_bt), then *scale[n] + bias[n]
// A: M x K bf16 row-major, B: N x K bf16 row-major, C: M x N fp32
// 128x128 tile, BK=32, 256 threads = 4 waves (2x2), each wave 64x64 = 4x4 MFMA tiles
__global__ __launch_bounds__(256) void gemm_sign_kernel(
    const unsigned short* __restrict__ A,
    const unsigned short* __restrict__ Bm,
    const float* __restrict__ scale,
    const float* __restrict__ bias,
    float* __restrict__ C) {
  __shared__ __align__(16) unsigned short smA[128 * 32];
  __shared__ __align__(16) unsigned short smB[128 * 32];

  const int tid  = threadIdx.x;
  const int lane = tid & 63;
  const int wave = tid >> 6;
  const int waveM = wave >> 1;          // 0..1
  const int waveN = wave & 1;           // 0..1
  const int lrow = lane & 15;           // fragment row/col within 16
  const int lk   = (lane >> 4) * 8;     // fragment k-offset (0,8,16,24)

  const int mBase = blockIdx.y * 128;
  const int nBase = blockIdx.x * 128;

  // staging: each thread moves one 16B chunk per issue; 2 issues per tile per matrix
  // LDS dest offset = tid*16 bytes (+4096 for issue 1): wave-uniform base + lane*16. 
  const int srow = tid >> 2;            // 0..63
  const int scol = (tid & 3) * 8;       // 0,8,16,24 (bf16 elements)
  const unsigned short* aSrc = A  + (size_t)(mBase + srow) * K_DIM + scol;
  const unsigned short* bSrc = Bm + (size_t)(nBase + srow) * K_DIM + scol;
  unsigned short* aDst = &smA[srow * 32 + scol];   // == smA + tid*8 elems
  unsigned short* bDst = &smB[srow * 32 + scol];
  const size_t rowStride64 = (size_t)64 * K_DIM;

  f32x4 acc[4][4];
#pragma unroll
  for (int i = 0; i < 4; ++i)
#pragma unroll
    for (int j = 0; j < 4; ++j)
      acc[i][j] = (f32x4){0.f, 0.f, 0.f, 0.f};

  for (int kt = 0; kt < K_DIM / 32; ++kt) {
    __syncthreads();  // all waves done reading the previous tile
    const unsigned short* aS = aSrc + kt * 32;
    const unsigned short* bS = bSrc + kt * 32;
    gld_lds16(aS,               aDst);
    gld_lds16(aS + rowStride64, aDst + 64 * 32);
    gld_lds16(bS,               bDst);
    gld_lds16(bS + rowStride64, bDst + 64 * 32);
    __syncthreads();  // compiler drains vmcnt before s_barrier

    bf16x8 af[4], bf[4];
#pragma unroll
    for (int mi = 0; mi < 4; ++mi)
      af[mi] = *(const bf16x8*)&smA[(waveM * 64 + mi * 16 + lrow) * 32 + lk];
#pragma unroll
    for (int ni = 0; ni < 4; ++ni)
      bf[ni] = *(const bf16x8*)&smB[(waveN * 64 + ni * 16 + lrow) * 32 + lk];
#pragma unroll
    for (int mi = 0; mi < 4; ++mi)
#pragma unroll
      for (int ni = 0; ni < 4; ++ni)
        acc[mi][ni] = __builtin_amdgcn_mfma_f32_16x16x32_bf16(
            af[mi], bf[ni], acc[mi][ni], 0, 0, 0);
  }

  // epilogue: C/D layout col = lane&15, row = (lane>>4)*4 + reg   [m89/m91]
#pragma unroll
  for (int ni = 0; ni < 4; ++ni) {
    const int c = nBase + waveN * 64 + ni * 16 + lrow;
    const float sc = scale[c];
    const float bs = bias[c];
#pragma unroll
    for (int mi = 0; mi < 4; ++mi) {
      const int r0 = mBase + waveM * 64 + mi * 16 + (lane >> 4) * 4;
#pragma unroll
      for (int r = 0; r < 4; ++r)
        C[(size_t)(r0 + r) * N_DIM + c] = acc[mi][ni][r] * sc + bs;
    }
  }
}

extern "C" void kernel_launch(void* const* d_in, const int* in_sizes, int n_in,
                              void* d_out, int out_size, void* d_ws, size_t ws_size,
                              hipStream_t stream) {
  const float* x     = (const float*)d_in[0];  // (B,S,IN) = (4,2048,4096) fp32
  const float* sign  = (const float*)d_in[1];  // (OUT,IN) = (4096,4096) fp32, values +/-1
  const float* scale = (const float*)d_in[2];  // (4096,)
  const float* bias  = (const float*)d_in[3];  // (4096,)
  float* out = (float*)d_out;                  // (B,S,OUT) fp32

  unsigned short* xb    = (unsigned short*)d_ws;            // M*K bf16 = 64 MiB
  unsigned short* signb = xb + (size_t)M_DIM * K_DIM;       // N*K bf16 = 32 MiB

  // casts: 4 elems/thread, 256 threads/block
  cvt_f32_bf16_kernel<<<(M_DIM * K_DIM) / 1024, 256, 0, stream>>>(x, xb);
  cvt_f32_bf16_kernel<<<(N_DIM * K_DIM) / 1024, 256, 0, stream>>>(sign, signb);

  dim3 grid(N_DIM / 128, M_DIM / 128);  // 32 x 64 = 2048 blocks
  gemm_sign_kernel<<<grid, 256, 0, stream>>>(xb, signb, scale, bias, out);
}

// Round 2
// 598.067 us; speedup vs baseline: 1.0120x; 1.0120x over previous
//
#include <hip/hip_runtime.h>

#define M_DIM 8192
#define N_DIM 4096
#define K_DIM 4096

typedef __attribute__((ext_vector_type(8))) short bf16x8;
typedef __attribute__((ext_vector_type(8))) unsigned short u16x8;
typedef __attribute__((ext_vector_type(4))) float f32x4;

__device__ inline unsigned short f32_to_bf16_rne(float f) {
  unsigned int u = __float_as_uint(f);
  u += 0x7FFFu + ((u >> 16) & 1u);   // round-to-nearest-even
  return (unsigned short)(u >> 16);
}

// fp32 -> bf16 cast, 8 elements/thread, 16B loads + 16B store
__global__ __launch_bounds__(256) void cvt_f32_bf16_kernel(
    const float* __restrict__ in, unsigned short* __restrict__ out) {
  const int i = (blockIdx.x * 256 + threadIdx.x) * 8;
  float4 v0 = *(const float4*)(in + i);
  float4 v1 = *(const float4*)(in + i + 4);
  u16x8 o;
  o[0] = f32_to_bf16_rne(v0.x);
  o[1] = f32_to_bf16_rne(v0.y);
  o[2] = f32_to_bf16_rne(v0.z);
  o[3] = f32_to_bf16_rne(v0.w);
  o[4] = f32_to_bf16_rne(v1.x);
  o[5] = f32_to_bf16_rne(v1.y);
  o[6] = f32_to_bf16_rne(v1.z);
  o[7] = f32_to_bf16_rne(v1.w);
  *(u16x8*)(out + i) = o;
}

__device__ inline void gld_lds16(const void* g, void* l) {
  __builtin_amdgcn_global_load_lds(
      (__attribute__((address_space(1))) void*)(g),
      (__attribute__((address_space(3))) void*)(l),
      16, 0, 0);
}

// C[m][n] = sum_k A[m][k] * B[n][k]  (gemm_bt), then *scale[n] + bias[n]
// 128x128 tile, BK=32, 256 threads = 4 waves (2x2), each wave 64x64 = 4x4 MFMA tiles.
// LDS layout XOR-swizzled: chunk stored at col (origCol ^ ((row>>1)&3)) so that
// ds_read_b128 fragment reads hit each 4-bank group exactly 2x (2-way = free, m136).
__global__ __launch_bounds__(256) void gemm_sign_kernel(
    const unsigned short* __restrict__ A,
    const unsigned short* __restrict__ Bm,
    const float* __restrict__ scale,
    const float* __restrict__ bias,
    float* __restrict__ C) {
  __shared__ __align__(16) unsigned short smA[128 * 32];
  __shared__ __align__(16) unsigned short smB[128 * 32];

  const int tid  = threadIdx.x;
  const int lane = tid & 63;
  const int wave = tid >> 6;
  const int waveM = wave >> 1;          // 0..1
  const int waveN = wave & 1;           // 0..1
  const int lrow = lane & 15;           // fragment row/col within 16
  const int mBase = blockIdx.y * 128;
  const int nBase = blockIdx.x * 128;

  // --- staging (swizzled source): LDS dest is fixed at tid*16B (wave-uniform+lane*16).
  // LDS position tid -> (row = tid>>2, storedCol = tid&3) holds global chunk
  // col = storedCol ^ ((row>>1)&3) = (tid&3) ^ ((tid>>3)&3).
  const int srow = tid >> 2;                              // 0..63
  const int gcol = ((tid & 3) ^ ((tid >> 3) & 3)) * 8;    // swizzled global chunk (elems)
  const unsigned short* aSrc = A  + (size_t)(mBase + srow) * K_DIM + gcol;
  const unsigned short* bSrc = Bm + (size_t)(nBase + srow) * K_DIM + gcol;
  unsigned short* aDst = smA + tid * 8;
  unsigned short* bDst = smB + tid * 8;
  const size_t rowStride64 = (size_t)64 * K_DIM;          // issue 1: rows 64..127 (swizzle
                                                          // phase unchanged: (row+64)>>1 & 3 == row>>1 & 3)

  f32x4 acc[4][4];
#pragma unroll
  for (int i = 0; i < 4; ++i)
#pragma unroll
    for (int j = 0; j < 4; ++j)
      acc[i][j] = (f32x4){0.f, 0.f, 0.f, 0.f};

  // --- fragment-read swizzle: row = base + lrow, (row>>1)&3 == (lrow>>1)&3 since
  // base is a multiple of 16. storedCol = origChunk(lane>>4) ^ ((lrow>>1)&3).
  const int storedCol = (((lane >> 4) ^ ((lrow >> 1) & 3))) * 8;  // elems

  for (int kt = 0; kt < K_DIM / 32; ++kt) {
    __syncthreads();  // all waves done reading the previous tile
    const unsigned short* aS = aSrc + kt * 32;
    const unsigned short* bS = bSrc + kt * 32;
    gld_lds16(aS,               aDst);
    gld_lds16(aS + rowStride64, aDst + 64 * 32);
    gld_lds16(bS,               bDst);
    gld_lds16(bS + rowStride64, bDst + 64 * 32);
    __syncthreads();  // compiler drains vmcnt before s_barrier

    bf16x8 af[4], bf[4];
#pragma unroll
    for (int mi = 0; mi < 4; ++mi)
      af[mi] = *(const bf16x8*)&smA[(waveM * 64 + mi * 16 + lrow) * 32 + storedCol];
#pragma unroll
    for (int ni = 0; ni < 4; ++ni)
      bf[ni] = *(const bf16x8*)&smB[(waveN * 64 + ni * 16 + lrow) * 32 + storedCol];
#pragma unroll
    for (int mi = 0; mi < 4; ++mi)
#pragma unroll
      for (int ni = 0; ni < 4; ++ni)
        acc[mi][ni] = __builtin_amdgcn_mfma_f32_16x16x32_bf16(
            af[mi], bf[ni], acc[mi][ni], 0, 0, 0);
  }

  // epilogue: C/D layout col = lane&15, row = (lane>>4)*4 + reg   [m89/m91]
#pragma unroll
  for (int ni = 0; ni < 4; ++ni) {
    const int c = nBase + waveN * 64 + ni * 16 + lrow;
    const float sc = scale[c];
    const float bs = bias[c];
#pragma unroll
    for (int mi = 0; mi < 4; ++mi) {
      const int r0 = mBase + waveM * 64 + mi * 16 + (lane >> 4) * 4;
#pragma unroll
      for (int r = 0; r < 4; ++r)
        C[(size_t)(r0 + r) * N_DIM + c] = acc[mi][ni][r] * sc + bs;
    }
  }
}

extern "C" void kernel_launch(void* const* d_in, const int* in_sizes, int n_in,
                              void* d_out, int out_size, void* d_ws, size_t ws_size,
                              hipStream_t stream) {
  const float* x     = (const float*)d_in[0];  // (B,S,IN) = (4,2048,4096) fp32
  const float* sign  = (const float*)d_in[1];  // (OUT,IN) = (4096,4096) fp32, +/-1
  const float* scale = (const float*)d_in[2];  // (4096,)
  const float* bias  = (const float*)d_in[3];  // (4096,)
  float* out = (float*)d_out;                  // (B,S,OUT) fp32

  unsigned short* xb    = (unsigned short*)d_ws;            // M*K bf16 = 64 MiB
  unsigned short* signb = xb + (size_t)M_DIM * K_DIM;       // N*K bf16 = 32 MiB

  // casts: 8 elems/thread
  cvt_f32_bf16_kernel<<<(M_DIM * K_DIM) / 2048, 256, 0, stream>>>(x, xb);
  cvt_f32_bf16_kernel<<<(N_DIM * K_DIM) / 2048, 256, 0, stream>>>(sign, signb);

  dim3 grid(N_DIM / 128, M_DIM / 128);  // 32 x 64 = 2048 blocks
  gemm_sign_kernel<<<grid, 256, 0, stream>>>(xb, signb, scale, bias, out);
}